// Round 2
// baseline (11.494 us; speedup 1.0000x reference)
//
#include <hip/hip_runtime.h>
#include <hip/hip_bf16.h>

// -sum_i( prob[i, target[i]] * reward[i] )
// N = 8192, C = 32000. prob: f32 (N,C), target: int32 (N,), reward: f32 (N,).
// Output: single f32 scalar.
//
// Single-dispatch version: one workgroup of 1024 threads (16 waves on 1 CU).
// Each thread handles 8 rows strided by 1024 (coalesced target/reward loads);
// the 8 scattered prob gathers are issued as independent loads for ILP.

#define BLK 1024
#define RPT 8  // rows per thread (BLK*RPT = 8192 = N)

__global__ __launch_bounds__(BLK) void ganloss_fused(
    const float* __restrict__ prob,
    const int* __restrict__ target,
    const float* __restrict__ reward,
    float* __restrict__ out,
    int N, int C) {
    const int tid = threadIdx.x;

    float acc = 0.0f;
    // Outer loop runs once for N=8192; kept for generality.
    for (int base = 0; base < N; base += BLK * RPT) {
        int   idx[RPT];
        float rw[RPT];
        float p[RPT];
        #pragma unroll
        for (int k = 0; k < RPT; ++k) {
            int i = base + k * BLK + tid;
            bool ok = (i < N);
            idx[k] = ok ? target[i] : 0;
            rw[k]  = ok ? reward[i] : 0.0f;
        }
        // Issue all scattered gathers back-to-back (independent, 8-deep ILP).
        #pragma unroll
        for (int k = 0; k < RPT; ++k) {
            int i = base + k * BLK + tid;
            p[k] = (i < N) ? prob[(size_t)i * (size_t)C + (size_t)idx[k]] : 0.0f;
        }
        #pragma unroll
        for (int k = 0; k < RPT; ++k)
            acc += p[k] * rw[k];
    }

    // Wave64 shuffle reduce.
    #pragma unroll
    for (int off = 32; off > 0; off >>= 1)
        acc += __shfl_down(acc, off, 64);

    __shared__ float smem[BLK / 64];  // 16 wave partials
    const int lane = tid & 63;
    const int w    = tid >> 6;
    if (lane == 0) smem[w] = acc;
    __syncthreads();

    if (w == 0) {
        float v = (lane < BLK / 64) ? smem[lane] : 0.0f;
        #pragma unroll
        for (int off = 8; off > 0; off >>= 1)
            v += __shfl_down(v, off, 64);
        if (lane == 0) out[0] = -v;
    }
}

extern "C" void kernel_launch(void* const* d_in, const int* in_sizes, int n_in,
                              void* d_out, int out_size, void* d_ws, size_t ws_size,
                              hipStream_t stream) {
    const float* prob   = (const float*)d_in[0];
    const int*   target = (const int*)d_in[1];
    const float* reward = (const float*)d_in[2];
    float* out = (float*)d_out;

    const int N = in_sizes[1];      // 8192
    const int C = in_sizes[0] / N;  // 32000

    ganloss_fused<<<1, BLK, 0, stream>>>(prob, target, reward, out, N, C);
}